// Round 1
// 272.594 us; speedup vs baseline: 1.2171x; 1.2171x over previous
//
#include <hip/hip_runtime.h>
#include <stdint.h>

#pragma clang fp contract(off)

#define BB 16
#define NN 25200
#define ROW 85
#define NCLS 80
#define TK 2048
#define SORTN 4096
#define NBIN 4096
#define MAXDET 1000
#define CONF 0.25f
#define IOUT 0.45f
#define MAXWH 4096.0f
#define SROWS 64

typedef float fvec4 __attribute__((ext_vector_type(4)));

#define AS1 __attribute__((address_space(1)))
#define AS3 __attribute__((address_space(3)))

// ---------------- Stage 1: coalesced LDS staging + scores + argmax + histogram ----------------
__global__ __launch_bounds__(64) void score_kernel(const float* __restrict__ pred,
                                                   float* __restrict__ scores,
                                                   int* __restrict__ cls,
                                                   unsigned int* __restrict__ hist) {
  __shared__ __align__(16) float srow[SROWS * ROW];  // 21760 B, one wave per block
  const int tile = blockIdx.x;
  const int b = blockIdx.y;
  const int lane = threadIdx.x;
  const int row0 = tile * SROWS;
  int nrows = NN - row0;
  if (nrows > SROWS) nrows = SROWS;
  const char* gsrc = (const char*)(pred + ((size_t)b * NN + row0) * ROW);
  const int nbytes = nrows * ROW * 4;
  // coalesced 16B/lane DMA: lds dest is wave-uniform base + lane*16 (linear)
  for (int off = lane * 16; off < nbytes; off += 64 * 16) {
    __builtin_amdgcn_global_load_lds((AS1 void*)(gsrc + off),
                                     (AS3 void*)((char*)srow + (off - lane * 16)),
                                     16, 0, 0);
  }
  __builtin_amdgcn_s_waitcnt(0);
  __syncthreads();
  if (lane < nrows) {
    const int n = row0 + lane;
    const float* r = srow + lane * ROW;   // stride 85 dwords -> 2-way bank alias (free)
    float obj = r[4];
    float best = r[5];
    int bid = 0;
#pragma unroll
    for (int c = 1; c < NCLS; ++c) {
      float p = r[5 + c];
      if (p > best) { best = p; bid = c; }   // strict > keeps first max (tie rule)
    }
    float score = obj * best;
    bool valid = (obj > CONF) && (score > CONF);
    float sout = valid ? score : 0.0f;
    scores[(size_t)b * NN + n] = sout;
    cls[(size_t)b * NN + n] = bid;
    if (valid) {
      unsigned int u = __float_as_uint(sout);        // in (0x3E800000, 0x3F800000)
      unsigned int bin = (u - 0x3E800001u) >> 12;
      if (bin > NBIN - 1) bin = NBIN - 1;
      atomicAdd(&hist[(size_t)b * NBIN + bin], 1u);
    }
  }
}

// ---------------- Stage 2: pivot + histogram-offset scatter + per-bin rank sort +
//                  emit top-2048 + per-class compaction (one block per batch) ----------------
__global__ __launch_bounds__(1024) void gather_kernel(const float* __restrict__ pred,
                                                      const float* __restrict__ scores,
                                                      const int* __restrict__ cls,
                                                      const unsigned int* __restrict__ hist,
                                                      float* __restrict__ tops,
                                                      float* __restrict__ boxes,
                                                      int* __restrict__ clsk,
                                                      int* __restrict__ keep,
                                                      int* __restrict__ cgrp,
                                                      int* __restrict__ coff) {
  const int b = blockIdx.x;
  const int t = threadIdx.x;
  const int w = t >> 6;
  const int lane = t & 63;
  __shared__ unsigned long long skey[SORTN];   // 32 KB
  __shared__ unsigned int sh[NBIN];            // 16 KB: counts -> scatter counters
  __shared__ unsigned int soff[NBIN];          // 16 KB: #candidates in strictly-higher bins
  __shared__ int spart[1024];
  __shared__ unsigned short scls[TK];
  __shared__ int ccnt[NCLS];
  __shared__ int coffs[NCLS + 1];
  __shared__ int sP;

  if (t == 0) sP = 0;
  for (int i = t; i < NBIN; i += 1024) sh[i] = hist[(size_t)b * NBIN + i];
  for (int i = t; i < SORTN; i += 1024) skey[i] = 0ull;
  __syncthreads();

  // ---- suffix-sum scan over bins (descending) + pivot ----
  int loc[4];
  int ssum = 0;
#pragma unroll
  for (int k = 0; k < 4; ++k) {
    loc[k] = (int)sh[NBIN - 1 - (4 * t + k)];
    ssum += loc[k];
  }
  spart[t] = ssum;
  __syncthreads();
  for (int o = 1; o < 1024; o <<= 1) {
    int v = (t >= o) ? spart[t - o] : 0;
    __syncthreads();
    spart[t] += v;
    __syncthreads();
  }
  int run = spart[t] - ssum;   // exclusive sum over higher bins
#pragma unroll
  for (int k = 0; k < 4; ++k) {
    int bin = NBIN - 1 - (4 * t + k);
    soff[bin] = (unsigned int)run;
    if (run < TK && run + loc[k] >= TK) sP = bin;   // unique bin satisfies this
    run += loc[k];
  }
  __syncthreads();
  const int P = sP;
  for (int i = t; i < NBIN; i += 1024) sh[i] = 0u;   // reuse as scatter counters
  __syncthreads();

  // ---- scatter candidates (bin >= P) to their bin segment ----
  const float* sc = scores + (size_t)b * NN;
  for (int n = t; n < NN; n += 1024) {
    unsigned int u = __float_as_uint(sc[n]);
    if (u > 0x3E800000u) {
      unsigned int bin = (u - 0x3E800001u) >> 12;
      if (bin > NBIN - 1) bin = NBIN - 1;
      if ((int)bin >= P) {
        unsigned int pos = soff[bin] + atomicAdd(&sh[bin], 1u);
        if (pos < SORTN)
          skey[pos] = ((unsigned long long)u << 32) | (unsigned int)(~n);
      }
    }
  }
  __syncthreads();

  // ---- per-bin exact sort (desc by (score_bits, ~idx)); one wave per bin ----
  for (int bin = P + w; bin < NBIN; bin += 16) {
    int s = (int)sh[bin];
    if (s < 2) continue;
    int base = (int)soff[bin];
    if (base >= SORTN) continue;
    if (base + s > SORTN) s = SORTN - base;
    if (s < 2) continue;
    if (s <= 64) {
      // ranking sort: all reads precede the (data-dependent) write; keys unique
      bool act = lane < s;
      unsigned long long key = act ? skey[base + lane] : 0ull;
      int rank = 0;
      for (int j = 0; j < s; ++j) {
        unsigned long long kj = skey[base + j];
        rank += (act && kj > key) ? 1 : 0;
      }
      if (act) skey[base + rank] = key;
    } else {
      // rare fallback: odd-even transposition (disjoint pairs per pass, same-wave DS in order)
      for (int pass = 0; pass < s; ++pass) {
        for (int p = base + (pass & 1) + 2 * lane; p + 1 < base + s; p += 128) {
          unsigned long long a = skey[p], b2 = skey[p + 1];
          if (a < b2) { skey[p] = b2; skey[p + 1] = a; }
        }
        asm volatile("" ::: "memory");
      }
    }
    asm volatile("" ::: "memory");
  }
  __syncthreads();

  // ---- emit top-2048 (exact stable top_k order) ----
  for (int i = t; i < TK; i += 1024) {
    unsigned long long key = skey[i];
    unsigned int ub = (unsigned int)(key >> 32);
    size_t gi = (size_t)b * TK + i;
    if (ub == 0u) {                 // padding (never with this data)
      tops[gi] = 0.0f;
      clsk[gi] = 0;
      keep[gi] = 0;
      fvec4 z; z[0] = 0.f; z[1] = 0.f; z[2] = 0.f; z[3] = 0.f;
      *(fvec4*)(boxes + gi * 4) = z;
      scls[i] = (unsigned short)0xFFFFu;
    } else {
      int idx = (int)(~(unsigned int)key);
      tops[gi] = __uint_as_float(ub);
      int cl = cls[(size_t)b * NN + idx];
      clsk[gi] = cl;
      scls[i] = (unsigned short)cl;
      const float* rowp = pred + ((size_t)b * NN + idx) * ROW;
      float cx = rowp[0], cy = rowp[1], w2 = rowp[2], h2 = rowp[3];
      float hw = w2 * 0.5f, hh = h2 * 0.5f;
      fvec4 bb4;
      bb4[0] = cx - hw; bb4[1] = cy - hh; bb4[2] = cx + hw; bb4[3] = cy + hh;
      *(fvec4*)(boxes + gi * 4) = bb4;
    }
  }
  __syncthreads();

  // ---- stable per-class compaction: wave w handles classes w, w+16, ... ----
#pragma unroll
  for (int k = 0; k < 5; ++k) {
    int c = w + 16 * k;
    int cnt = 0;
    for (int base2 = 0; base2 < TK; base2 += 64) {
      bool match = ((int)scls[base2 + lane] == c);
      cnt += (int)__popcll(__ballot(match));
    }
    if (lane == 0) ccnt[c] = cnt;
  }
  __syncthreads();
  if (t == 0) {
    int r2 = 0;
    for (int c = 0; c < NCLS; ++c) { coffs[c] = r2; r2 += ccnt[c]; }
    coffs[NCLS] = r2;
  }
  __syncthreads();
#pragma unroll
  for (int k = 0; k < 5; ++k) {
    int c = w + 16 * k;
    int run2 = coffs[c];
    for (int base2 = 0; base2 < TK; base2 += 64) {
      bool match = ((int)scls[base2 + lane] == c);
      unsigned long long bal = __ballot(match);
      int r3 = (int)__popcll(bal & ((1ull << lane) - 1ull));
      if (match) cgrp[(size_t)b * TK + run2 + r3] = base2 + lane;
      run2 += (int)__popcll(bal);
    }
  }
  for (int c = t; c <= NCLS; c += 1024) coff[b * (NCLS + 1) + c] = coffs[c];
}

// ---------------- Stage 3: greedy NMS, one wave per (batch, class), contiguous list ----------------
__global__ __launch_bounds__(64) void nms_kernel(const float* __restrict__ tops,
                                                 const float* __restrict__ boxes,
                                                 const int* __restrict__ cgrp,
                                                 const int* __restrict__ coff,
                                                 int* __restrict__ keep) {
  const int c = blockIdx.x;
  const int b = blockIdx.y;
  const int lane = threadIdx.x;
  const int start = coff[b * (NCLS + 1) + c];
  const int end = coff[b * (NCLS + 1) + c + 1];
  const int m = end - start;
  if (m <= 0) return;
  __shared__ float sx1[TK], sy1[TK], sx2[TK], sy2[TK];
  __shared__ unsigned short spos[TK];
  __shared__ unsigned char skp[TK];

  const float shift = (float)c * MAXWH;
  for (int i = lane; i < m; i += 64) {
    int j = cgrp[(size_t)b * TK + start + i];
    fvec4 bx = *(const fvec4*)(boxes + ((size_t)b * TK + j) * 4);
    sx1[i] = bx[0] + shift;
    sy1[i] = bx[1] + shift;
    sx2[i] = bx[2] + shift;
    sy2[i] = bx[3] + shift;
    spos[i] = (unsigned short)j;
    skp[i] = (tops[(size_t)b * TK + j] > 0.0f) ? 1 : 0;
  }
  __syncthreads();

  for (int i = 0; i < m; ++i) {
    __syncthreads();
    if (!skp[i]) continue;  // uniform across the wave
    float ax1 = sx1[i], ay1 = sy1[i], ax2 = sx2[i], ay2 = sy2[i];
    float aarea = (ax2 - ax1) * (ay2 - ay1);
    for (int j = i + 1 + lane; j < m; j += 64) {
      float bx1 = sx1[j], by1 = sy1[j], bx2 = sx2[j], by2 = sy2[j];
      float ltx = fmaxf(ax1, bx1), lty = fmaxf(ay1, by1);
      float rbx = fminf(ax2, bx2), rby = fminf(ay2, by2);
      float iw = fmaxf(rbx - ltx, 0.0f);
      float ih = fmaxf(rby - lty, 0.0f);
      float inter = iw * ih;
      float barea = (bx2 - bx1) * (by2 - by1);
      float iou = inter / (aarea + barea - inter + 1e-7f);
      if (iou > IOUT) skp[j] = 0;
    }
  }
  __syncthreads();

  for (int i = lane; i < m; i += 64) {
    keep[(size_t)b * TK + spos[i]] = skp[i];
  }
}

// ---------------- Stage 4: compact first 1000 kept + padding ----------------
__global__ __launch_bounds__(256) void out_kernel(const float* __restrict__ tops,
                                                  const float* __restrict__ boxes,
                                                  const int* __restrict__ clsk,
                                                  const int* __restrict__ keep,
                                                  float* __restrict__ out) {
  int b = blockIdx.x;
  int t = threadIdx.x;
  __shared__ int scnt[256];
  const int CH = TK / 256;  // 8
  int base = t * CH;
  int kp[CH];
  int cnt = 0;
  for (int k = 0; k < CH; ++k) {
    kp[k] = keep[(size_t)b * TK + base + k];
    cnt += kp[k];
  }
  scnt[t] = cnt;
  __syncthreads();
  for (int off = 1; off < 256; off <<= 1) {
    int v = (t >= off) ? scnt[t - off] : 0;
    __syncthreads();
    scnt[t] += v;
    __syncthreads();
  }
  int r = scnt[t] - cnt;
  int K = scnt[255];
  for (int k = 0; k < CH; ++k) {
    if (kp[k]) {
      if (r < MAXDET) {
        int j = base + k;
        float* o = out + ((size_t)b * MAXDET + r) * 6;
        const float* bx = boxes + ((size_t)b * TK + j) * 4;
        o[0] = bx[0]; o[1] = bx[1]; o[2] = bx[2]; o[3] = bx[3];
        o[4] = tops[(size_t)b * TK + j];
        o[5] = (float)clsk[(size_t)b * TK + j];
      }
      ++r;
    }
  }
  int Kc = K < MAXDET ? K : MAXDET;
  for (int r2 = Kc + t; r2 < MAXDET; r2 += 256) {
    float* o = out + ((size_t)b * MAXDET + r2) * 6;
    o[0] = 0.0f; o[1] = 0.0f; o[2] = 0.0f; o[3] = 0.0f; o[4] = 0.0f; o[5] = -1.0f;
  }
}

extern "C" void kernel_launch(void* const* d_in, const int* in_sizes, int n_in,
                              void* d_out, int out_size, void* d_ws, size_t ws_size,
                              hipStream_t stream) {
  const float* pred = (const float*)d_in[0];
  float* out = (float*)d_out;

  char* ws = (char*)d_ws;
  size_t off = 0;
  float* scores = (float*)(ws + off); off += (size_t)BB * NN * 4;
  int*   cls    = (int*)(ws + off);   off += (size_t)BB * NN * 4;
  float* tops   = (float*)(ws + off); off += (size_t)BB * TK * 4;
  float* boxes  = (float*)(ws + off); off += (size_t)BB * TK * 16;
  int*   clsk   = (int*)(ws + off);   off += (size_t)BB * TK * 4;
  int*   keep   = (int*)(ws + off);   off += (size_t)BB * TK * 4;
  unsigned int* hist = (unsigned int*)(ws + off); off += (size_t)BB * NBIN * 4;
  int*   cgrp   = (int*)(ws + off);   off += (size_t)BB * TK * 4;
  int*   coff   = (int*)(ws + off);   off += (size_t)BB * (NCLS + 1) * 4;
  (void)ws_size; (void)in_sizes; (void)n_in; (void)out_size;

  hipMemsetAsync(hist, 0, (size_t)BB * NBIN * 4, stream);
  score_kernel<<<dim3((NN + SROWS - 1) / SROWS, BB), 64, 0, stream>>>(pred, scores, cls, hist);
  gather_kernel<<<BB, 1024, 0, stream>>>(pred, scores, cls, hist, tops, boxes, clsk, keep, cgrp, coff);
  nms_kernel<<<dim3(NCLS, BB), 64, 0, stream>>>(tops, boxes, cgrp, coff, keep);
  out_kernel<<<BB, 256, 0, stream>>>(tops, boxes, clsk, keep, out);
}